// Round 5
// baseline (97.222 us; speedup 1.0000x reference)
//
#include <hip/hip_runtime.h>

// DTW wavefront kernel for MI355X (gfx950). Round 5.
// B=32, N=32, D=12, P=32, L=1024, L_OUT=32, RHO=1 => w=1.
// D[i,j] = c[i,j] + min3(D[i-1,j-1], D[i-1,j], D[i,j-1]).
// Round-5: skewed super-steps. Lane i processes 4 columns per super-step
// (lag 4 between adjacent lanes). Cross-lane traffic = 4 dpp per super-step,
// OFF the per-column chain (r4 evidence: dependent dpp ~70cyc dominated the
// 1055-step recurrence). Per-column chain = v_min + v_add only.
// Producer wave (MFMA bf16 cross + fp32 p2/x2) fills a 4-chunk (256-col)
// LDS ring, rotated +3 so consumer ds_read_b128 blocks are 16B-aligned.

#define BIGF 1e30f
#define LL   1024
#define LOUT 32
#define RSTR 260         // cbuf row stride in floats (256-col ring + 4 pad)
#define RING 256
#define NCH  16          // 64-column chunks

using v4f   = __attribute__((ext_vector_type(4))) float;
using s16x8 = __attribute__((ext_vector_type(8))) short;   // 8 bf16

__device__ __forceinline__ float wshr1(float v) {
    // whole-wave shift: lane i <- lane i-1 (lane 0 <- old=0), VALU dpp
    int r = __builtin_amdgcn_update_dpp(0, __float_as_int(v), 0x138 /*wave_shr:1*/,
                                        0xF, 0xF, false);
    return __int_as_float(r);
}

__device__ __forceinline__ short f2bf(float f) {   // fp32 -> bf16 RNE
    unsigned u = __float_as_uint(f);
    u += 0x7FFF + ((u >> 16) & 1);
    return (short)(u >> 16);
}

// One super-step: 4 columns. U values come from prev super-step's outputs O
// of lane i-1 (4 dpp). Per-column chain: D_s = c_s + min(Um_s, D_{s-1}).
template<bool READ, bool STORE, bool FIX>
__device__ __forceinline__ void sstep(v4f& O, float& Dloc, float& Uc, v4f& q,
                                      const float* crow, int& roff, bool l0,
                                      int& jcur, float* lds_out, int outbase) {
    float U0 = wshr1(O.x), U1 = wshr1(O.y), U2 = wshr1(O.z), U3 = wshr1(O.w);
    if (l0) { U0 = BIGF; U1 = BIGF; U2 = BIGF; U3 = BIGF; }  // row -1 boundary
    float Um0 = fminf(Uc, U0);
    float Um1 = fminf(U0, U1);
    float Um2 = fminf(U1, U2);
    float Um3 = fminf(U2, U3);
    if (FIX) Um3 = l0 ? 0.0f : Um3;     // virtual D[-1,-1]=0 -> D[0,0]=c[0,0]
    Uc = U3;
    v4f c = q;
    if (READ) { q = *(const v4f*)(crow + roff); roff = (roff + 4) & (RING - 1); }
    float D0 = c.x + fminf(Um0, Dloc);
    float D1 = c.y + fminf(Um1, D0);
    float D2 = c.z + fminf(Um2, D1);
    float D3 = c.w + fminf(Um3, D2);
    Dloc = D3;
    O.x = D0; O.y = D1; O.z = D2; O.w = D3;
    if (STORE) {
        unsigned j0 = (unsigned)(jcur - (LL - LOUT));   // wraps for jcur<992
        if (j0 + 0u < 32u) lds_out[outbase + (j0 + 0u)] = D0;
        if (j0 + 1u < 32u) lds_out[outbase + (j0 + 1u)] = D1;
        if (j0 + 2u < 32u) lds_out[outbase + (j0 + 2u)] = D2;
        if (j0 + 3u < 32u) lds_out[outbase + (j0 + 3u)] = D3;
        jcur += 4;
    }
}

// One group = 16 super-steps = one 64-column chunk of wavefront advance.
// Reads: prime 4 quads, then super-steps m=0..11 each read for m+4.
// Max ring pos read-issued in group g is 64g+63 < producer's 64g+67. No race.
template<bool STORE, bool FIX0>
__device__ __forceinline__ void run_group(v4f& O, float& Dloc, float& Uc,
                                          const float* crow, int& roff, bool l0,
                                          int& jcur, float* lds_out, int outbase) {
    v4f q0 = *(const v4f*)(crow + roff);
    v4f q1 = *(const v4f*)(crow + ((roff + 4) & (RING - 1)));
    v4f q2 = *(const v4f*)(crow + ((roff + 8) & (RING - 1)));
    v4f q3 = *(const v4f*)(crow + ((roff + 12) & (RING - 1)));
    roff = (roff + 16) & (RING - 1);
    sstep<true, STORE, FIX0 >(O, Dloc, Uc, q0, crow, roff, l0, jcur, lds_out, outbase);
    sstep<true, STORE, false>(O, Dloc, Uc, q1, crow, roff, l0, jcur, lds_out, outbase);
    sstep<true, STORE, false>(O, Dloc, Uc, q2, crow, roff, l0, jcur, lds_out, outbase);
    sstep<true, STORE, false>(O, Dloc, Uc, q3, crow, roff, l0, jcur, lds_out, outbase);
#pragma unroll
    for (int rep = 0; rep < 2; ++rep) {
        sstep<true, STORE, false>(O, Dloc, Uc, q0, crow, roff, l0, jcur, lds_out, outbase);
        sstep<true, STORE, false>(O, Dloc, Uc, q1, crow, roff, l0, jcur, lds_out, outbase);
        sstep<true, STORE, false>(O, Dloc, Uc, q2, crow, roff, l0, jcur, lds_out, outbase);
        sstep<true, STORE, false>(O, Dloc, Uc, q3, crow, roff, l0, jcur, lds_out, outbase);
    }
    sstep<false, STORE, false>(O, Dloc, Uc, q0, crow, roff, l0, jcur, lds_out, outbase);
    sstep<false, STORE, false>(O, Dloc, Uc, q1, crow, roff, l0, jcur, lds_out, outbase);
    sstep<false, STORE, false>(O, Dloc, Uc, q2, crow, roff, l0, jcur, lds_out, outbase);
    sstep<false, STORE, false>(O, Dloc, Uc, q3, crow, roff, l0, jcur, lds_out, outbase);
}

__global__ __launch_bounds__(128) void dtw_kernel(const float* __restrict__ x,
                                                  const float* __restrict__ patts,
                                                  float* __restrict__ out) {
    __shared__ float cbuf[64 * RSTR];          // 66.6 KB: 64 rows x 256-col ring
    __shared__ float x2s[LL];                  // 4 KB
    __shared__ float p2s[64];
    __shared__ float lds_out[2 * 32 * LOUT];   // 8 KB

    const int tid  = threadIdx.x;
    const int wid  = tid >> 6;        // 0 = producer, 1 = consumer
    const int lane = tid & 63;
    const int li   = lane & 31;
    const int half = lane >> 5;
    const int q    = lane >> 4;       // mfma quad (producer)
    const int c16  = lane & 15;
    const bool l0  = (li == 0);
    const int blk = blockIdx.x;
    const int b   = blk >> 4;
    const int n0  = (blk & 15) << 1;

    const float* __restrict__ xb = x + b * (12 * LL);

    // ---- prefill ring with 0.0 (exact BIG-propagation in ramp; no NaN risk) ----
    {
        float* rp = cbuf + (tid >> 1) * RSTR + (tid & 1) * 128;
        v4f z = {0.f, 0.f, 0.f, 0.f};
#pragma unroll
        for (int k = 0; k < 32; ++k) *(v4f*)(rp + 4 * k) = z;
    }

    // ---- x2s[j] = sum_d x[b][d][j]^2, split across both waves ----
#pragma unroll 1
    for (int k = 0; k < 8; k += 2) {
        int col0 = (wid * 8 + k) * 64 + lane;
        int col1 = col0 + 64;
        float a0 = 0.f, a1 = 0.f;
#pragma unroll
        for (int d = 0; d < 12; ++d) {
            float v = xb[d * LL + col0]; a0 += v * v;
            float w = xb[d * LL + col1]; a1 += w * w;
        }
        x2s[col0] = a0; x2s[col1] = a1;
    }

    // ---- producer-only setup ----
    s16x8 afrag[4];
    float p2r[4][4];
    float xpre[4][8];
    if (wid == 0) {
        {
            const float* pn = patts + (n0 + half) * (12 * 32);
            float acc = 0.f;
#pragma unroll
            for (int d = 0; d < 12; ++d) { float v = pn[d * 32 + li]; acc += v * v; }
            p2s[lane] = acc;
        }
#pragma unroll
        for (int m = 0; m < 4; ++m) {
            int row = 16 * m + c16;
            const float* pm = patts + (n0 + (row >> 5)) * (12 * 32);
            int i = row & 31;
#pragma unroll
            for (int e = 0; e < 8; ++e) {
                int d = q * 8 + e;
                afrag[m][e] = f2bf(d < 12 ? pm[d * 32 + i] : 0.f);
            }
        }
#pragma unroll
        for (int m = 0; m < 4; ++m)
#pragma unroll
            for (int r = 0; r < 4; ++r) p2r[m][r] = p2s[16 * m + q * 4 + r];
#pragma unroll
        for (int tl = 0; tl < 4; ++tl)
#pragma unroll
            for (int e = 0; e < 8; ++e) {
                int d = q * 8 + e;
                xpre[tl][e] = (d < 12) ? xb[d * LL + (16 * tl + c16)] : 0.f;
            }
    }

    auto produce = [&](int c) {
        s16x8 bf[4];
#pragma unroll
        for (int tl = 0; tl < 4; ++tl)
#pragma unroll
            for (int e = 0; e < 8; ++e) bf[tl][e] = f2bf(xpre[tl][e]);
        if (c + 1 < NCH) {
            const int j1 = (c + 1) * 64;
#pragma unroll
            for (int tl = 0; tl < 4; ++tl)
#pragma unroll
                for (int e = 0; e < 8; ++e) {
                    int d = q * 8 + e;
                    if (d < 12) xpre[tl][e] = xb[d * LL + (j1 + 16 * tl + c16)];
                }
        }
        const int j0 = c * 64;
#pragma unroll
        for (int tl = 0; tl < 4; ++tl) {
            float x2v = x2s[j0 + 16 * tl + c16];
            int colin = (j0 + 16 * tl + c16 + 3) & (RING - 1);   // +3 ring rotation
#pragma unroll
            for (int m = 0; m < 4; ++m) {
                v4f z = {0.f, 0.f, 0.f, 0.f};
                v4f acc = __builtin_amdgcn_mfma_f32_16x16x32_bf16(afrag[m], bf[tl], z, 0, 0, 0);
                // C-frag: col = lane&15, row = 16m + 4q + r
                float* wb = &cbuf[(16 * m + q * 4) * RSTR + colin];
#pragma unroll
                for (int r = 0; r < 4; ++r)
                    wb[r * RSTR] = p2r[m][r] + x2v - 2.0f * acc[r];
            }
        }
    };

    // ---- consumer DP state ----
    v4f   O    = {BIGF, BIGF, BIGF, BIGF};
    float Dloc = BIGF, Uc = BIGF;
    int   roff = (-(4 * li)) & (RING - 1);
    int   jcur = 957 - 4 * li;            // column base at k=240 (store groups)
    const float* crow = cbuf + lane * RSTR;
    const int outbase = half * (32 * LOUT) + li * LOUT;

    __syncthreads();                 // prefill + x2s ready
    if (wid == 0) produce(0);
    __syncthreads();                 // chunk 0 ready

#pragma unroll 1
    for (int g = 0; g < 18; ++g) {
        if (wid == 0) {
            if (g <= 14) produce(g + 1);
        } else {
            if (g == 0)
                run_group<false, true >(O, Dloc, Uc, crow, roff, l0, jcur, lds_out, outbase);
            else if (g < 15)
                run_group<false, false>(O, Dloc, Uc, crow, roff, l0, jcur, lds_out, outbase);
            else
                run_group<true,  false>(O, Dloc, Uc, crow, roff, l0, jcur, lds_out, outbase);
        }
        __syncthreads();
    }

    // ---- coalesced flush: 2048 floats, 128 threads ----
    float* ob = out + blk * (2 * 32 * LOUT);
#pragma unroll
    for (int r = 0; r < 4; ++r) {
        int idx = r * 512 + tid * 4;
        v4f v = *(const v4f*)(&lds_out[idx]);
        *(v4f*)(ob + idx) = v;
    }
}

extern "C" void kernel_launch(void* const* d_in, const int* in_sizes, int n_in,
                              void* d_out, int out_size, void* d_ws, size_t ws_size,
                              hipStream_t stream) {
    const float* x     = (const float*)d_in[0];   // [32,12,1024] f32
    const float* patts = (const float*)d_in[1];   // [32,12,32]   f32
    float* out         = (float*)d_out;           // [32,32,32,32] f32
    dtw_kernel<<<dim3(512), dim3(128), 0, stream>>>(x, patts, out);
}